// Round 2
// baseline (2679.376 us; speedup 1.0000x reference)
//
#include <hip/hip_runtime.h>
#include <cstdint>
#include <cstddef>

#pragma clang fp contract(off)

#ifndef EXP_VARIANT
#define EXP_VARIANT 2
#endif

constexpr int NIMG  = 16;
constexpr int NB0   = 19200;   // 80*80*3
constexpr int NB1   = 4800;    // 40*40*3
constexpr int NB2   = 1200;    // 20*20*3
constexpr int NBOX  = 25200;
constexpr int NCLS  = 80;
constexpr int NCH   = 85;
constexpr int NBINS = 4096;
constexpr int CAP   = 4096;
constexpr int NTOP  = 1000;
constexpr int NDET  = 100;
constexpr float IMGSZ = 640.0f;
constexpr float BIN_SCALE = 4096.0f / 0.75f;

constexpr int CHUNK   = 64;            // boxes per LDS chunk
constexpr int CHUNK_F = CHUNK * NCH;   // 5440 floats
constexpr int TILE    = 512;           // boxes per block (8 chunks)
constexpr int TILES   = (NBOX + TILE - 1) / TILE;   // 50

// ---------------- XLA-CPU-matching transcendentals (verified absmax=0) ----------------
__device__ __forceinline__ float xla_expf(float x) {
  const float kLog2e = 1.44269504088896341f;
  const float kC1 = 0.693359375f;
  const float kC2 = -2.12194440e-4f;
  const float cp0 = 1.9875691500e-4f;
  const float cp1 = 1.3981999507e-3f;
  const float cp2 = 8.3334519073e-3f;
  const float cp3 = 4.1665795894e-2f;
  const float cp4 = 1.6666665459e-1f;
  const float cp5 = 5.0000001201e-1f;
  float xc = fminf(x, 88.3762626647950f);
  xc = fmaxf(xc, -88.3762626647949f);
  float fx = floorf(fmaf(xc, kLog2e, 0.5f));
  float xr = fmaf(fx, -kC1, xc);
  xr = fmaf(fx, -kC2, xr);
  float z = xr * xr;
  float y = fmaf(cp0, xr, cp1);
  y = fmaf(y, xr, cp2);
  y = fmaf(y, xr, cp3);
  y = fmaf(y, xr, cp4);
  y = fmaf(y, xr, cp5);
  y = fmaf(y, z, xr);
  y = y + 1.0f;
  int n = (int)fx;
  float two_n = __int_as_float((n + 127) << 23);
  float r = y * two_n;
  return fmaxf(r, xc);
}

__device__ __forceinline__ float ref_sigmoid(float x) {
  return 1.0f / (1.0f + xla_expf(-x));
}

// ---------------- geometry helpers ----------------
__device__ __forceinline__ const float* locate(int img, int box,
    const float* __restrict__ p0, const float* __restrict__ p1, const float* __restrict__ p2,
    int& lvl, int& gx, int& gy, int& anc, float& stride) {
  const float* base; int r, W;
  if (box < NB0)            { lvl = 0; r = box;             W = 80; base = p0 + (size_t)img * NB0 * NCH; stride = 8.0f;  }
  else if (box < NB0 + NB1) { lvl = 1; r = box - NB0;       W = 40; base = p1 + (size_t)img * NB1 * NCH; stride = 16.0f; }
  else                      { lvl = 2; r = box - NB0 - NB1; W = 20; base = p2 + (size_t)img * NB2 * NCH; stride = 32.0f; }
  anc = r % 3;
  int cell = r / 3;
  gx = cell % W;
  gy = cell / W;
  return base + (size_t)r * NCH;
}

__device__ __forceinline__ float clip640(float v) {
  return fminf(fmaxf(v, 0.0f), IMGSZ);
}

// chunk (64 aligned boxes) never straddles a level boundary: 19200, 24000 are multiples of 64
__device__ __forceinline__ const float* chunk_ptr(int img, int first_box, int nb,
    const float* __restrict__ p0, const float* __restrict__ p1, const float* __restrict__ p2) {
  const float* base; int r;
  if (first_box < NB0)            { base = p0 + (size_t)img * NB0 * NCH; r = first_box; }
  else if (first_box < NB0 + NB1) { base = p1 + (size_t)img * NB1 * NCH; r = first_box - NB0; }
  else                            { base = p2 + (size_t)img * NB2 * NCH; r = first_box - NB0 - NB1; }
  return base + (size_t)r * NCH;
}

// ---------------- pass A: stream input once, histogram + per-box maxbin ----------------
__global__ __launch_bounds__(256) void k_passA(const float* __restrict__ p0,
    const float* __restrict__ p1, const float* __restrict__ p2,
    unsigned int* __restrict__ ghist, unsigned short* __restrict__ maxbin) {
  __shared__ __align__(16) float buf[2][CHUNK_F];
  __shared__ unsigned int hist[NBINS];
  const int tid = threadIdx.x;
  const int img  = blockIdx.x / TILES;
  const int tile = blockIdx.x % TILES;
  const int tbase = tile * TILE;
  const int nbox_tile = min(TILE, NBOX - tbase);
  const int nch = (nbox_tile + CHUNK - 1) / CHUNK;

  for (int i = tid; i < NBINS; i += 256) hist[i] = 0u;

  float4 regs[6];
  // prologue: load chunk 0 into buf[0]
  {
    int nb0c = min(CHUNK, nbox_tile);
    const float* cp = chunk_ptr(img, tbase, nb0c, p0, p1, p2);
    int nv = (nb0c * NCH) / 4;
    const float4* cp4 = (const float4*)cp;
    float4* b4 = (float4*)&buf[0][0];
    #pragma unroll
    for (int k = 0; k < 6; ++k) { int i = tid + k * 256; if (i < nv) regs[k] = cp4[i]; }
    #pragma unroll
    for (int k = 0; k < 6; ++k) { int i = tid + k * 256; if (i < nv) b4[i] = regs[k]; }
  }
  __syncthreads();

  for (int c = 0; c < nch; ++c) {
    // issue prefetch of chunk c+1
    int nvN = 0;
    if (c + 1 < nch) {
      int fb = tbase + (c + 1) * CHUNK;
      int nbN = min(CHUNK, NBOX - fb);
      const float* cp = chunk_ptr(img, fb, nbN, p0, p1, p2);
      nvN = (nbN * NCH) / 4;
      const float4* cp4 = (const float4*)cp;
      #pragma unroll
      for (int k = 0; k < 6; ++k) { int i = tid + k * 256; if (i < nvN) regs[k] = cp4[i]; }
    }
    // compute on buf[c&1]
    {
      int nb = min(CHUNK, nbox_tile - c * CHUNK);
      int b = tid >> 2, part = tid & 3;
      if (b < nb) {
        const float* row = &buf[c & 1][b * NCH];
        float obj = ref_sigmoid(row[4]);
        int mb = 0;
        if (obj > 0.25f) {
          float rr = 0.25f / obj;
          float tcons = __logf(rr / (1.0f - rr)) - 0.01f;   // conservative pre-filter
          const float* cls = row + 5 + part * 20;
          #pragma unroll 4
          for (int cc = 0; cc < 20; ++cc) {
            float x = cls[cc];
            if (x > tcons) {
              float s = obj * ref_sigmoid(x);               // exact path, identical to round 1
              if (s > 0.25f) {
                int bin = (int)((s - 0.25f) * BIN_SCALE);
                bin = min(bin, NBINS - 1);
                atomicAdd(&hist[bin], 1u);
                mb = max(mb, bin + 1);                      // stored = maxbin+1, 0 = none
              }
            }
          }
        }
        mb = max(mb, __shfl_xor(mb, 1, 4));
        mb = max(mb, __shfl_xor(mb, 2, 4));
        if (part == 0)
          maxbin[(size_t)img * NBOX + tbase + c * CHUNK + b] = (unsigned short)mb;
      }
    }
    // stage prefetched chunk into the other buffer
    if (c + 1 < nch) {
      float4* b4 = (float4*)&buf[(c + 1) & 1][0];
      #pragma unroll
      for (int k = 0; k < 6; ++k) { int i = tid + k * 256; if (i < nvN) b4[i] = regs[k]; }
    }
    __syncthreads();
  }

  for (int i = tid; i < NBINS; i += 256) {
    unsigned int v = hist[i];
    if (v) atomicAdd(&ghist[img * NBINS + i], v);
  }
}

// ---------------- pass B: per-image tbin + candidate key emission ----------------
__global__ __launch_bounds__(256) void k_passB(const float* __restrict__ p0,
    const float* __restrict__ p1, const float* __restrict__ p2,
    const unsigned int* __restrict__ ghist, const unsigned short* __restrict__ maxbin,
    unsigned long long* __restrict__ cand, int* __restrict__ cnt) {
  __shared__ unsigned int h[NBINS];
  __shared__ unsigned int psum[256];
  __shared__ int tb_sh;
  const int tid = threadIdx.x;
  const int img = blockIdx.x;

  for (int i = tid; i < NBINS; i += 256) h[i] = ghist[img * NBINS + i];
  __syncthreads();
  unsigned int ps = 0;
  for (int k = 0; k < 16; ++k) ps += h[tid * 16 + k];
  psum[tid] = ps;
  __syncthreads();
  if (tid == 0) {
    long long cum = 0;
    int tb = 0;
    bool found = false;
    for (int g = 255; g >= 0 && !found; --g) {
      if (cum + (long long)psum[g] >= NTOP) {
        for (int b = g * 16 + 15; b >= g * 16; --b) {
          cum += h[b];
          if (cum >= NTOP) { tb = b; found = true; break; }
        }
      } else {
        cum += psum[g];
      }
    }
    if (!found) tb = 0;
    while (cum > CAP && tb < NBINS - 1) { cum -= h[tb]; ++tb; }
    tb_sh = tb;
  }
  __syncthreads();
  const int tb = tb_sh;

  for (int box = tid; box < NBOX; box += 256) {
    int mb = (int)maxbin[(size_t)img * NBOX + box];
    if (mb <= tb) continue;                    // mb = maxbin+1 > tb  <=>  maxbin >= tb
    int lvl, gx, gy, anc; float stride;
    const float* ptr = locate(img, box, p0, p1, p2, lvl, gx, gy, anc, stride);
    float obj = ref_sigmoid(ptr[4]);
    if (obj <= 0.25f) continue;
    float rr = 0.25f / obj;
    float tcons = __logf(rr / (1.0f - rr)) - 0.01f;
    for (int c = 0; c < NCLS; ++c) {
      float x = ptr[5 + c];
      if (x <= tcons) continue;
      float s = obj * ref_sigmoid(x);
      if (s > 0.25f) {
        int bin = (int)((s - 0.25f) * BIN_SCALE);
        bin = min(bin, NBINS - 1);
        if (bin >= tb) {
          int pos = atomicAdd(&cnt[img], 1);
          if (pos < CAP) {
            unsigned int fi = (unsigned int)(box * NCLS + c);
            unsigned long long key =
                ((unsigned long long)__float_as_uint(s) << 32) |
                (unsigned long long)(0xFFFFFFFFu - fi);
            cand[(size_t)img * CAP + pos] = key;
          }
        }
      }
    }
  }
}

// ---------------- fused sort + NMS (one block per image) ----------------
__global__ __launch_bounds__(1024) void k_sortnms(const float* __restrict__ p0,
    const float* __restrict__ p1, const float* __restrict__ p2,
    const float* __restrict__ anchors, const unsigned long long* __restrict__ cand,
    const int* __restrict__ cnt_arr, const float* __restrict__ scalef,
    float* __restrict__ out) {
  __shared__ unsigned long long keys[CAP];   // 32 KB
  __shared__ float bxs[NTOP][4];             // 16 KB
  __shared__ float val[NTOP];                //  4 KB
  __shared__ int   lab[NTOP];                //  4 KB
  __shared__ int   n2_sh, cnt_sh;
  const int tid = threadIdx.x;
  const int img = blockIdx.x;

  if (tid == 0) {
    int c = cnt_arr[img];
    c = max(0, min(c, CAP));
    int n2 = 1024;
    while (n2 < c) n2 <<= 1;
    cnt_sh = c; n2_sh = n2;
  }
  __syncthreads();
  const int cnt = cnt_sh;
  const int n2  = n2_sh;

  const unsigned long long* c = cand + (size_t)img * CAP;
  for (int i = tid; i < n2; i += 1024) keys[i] = (i < cnt) ? c[i] : 0ull;
  __syncthreads();

  for (int kk = 2; kk <= n2; kk <<= 1) {
    for (int j = kk >> 1; j > 0; j >>= 1) {
      for (int i = tid; i < n2; i += 1024) {
        int l = i ^ j;
        if (l > i) {
          unsigned long long a = keys[i], b = keys[l];
          bool up = ((i & kk) == 0);
          bool sw = up ? (a < b) : (a > b);
          if (sw) { keys[i] = b; keys[l] = a; }
        }
      }
      __syncthreads();
    }
  }

  // decode top-1000
  if (tid < NTOP) {
    unsigned long long key = keys[tid];
    unsigned int v = (unsigned int)(key >> 32);
    val[tid] = __uint_as_float(v);
    if (v) {
      unsigned int idx = 0xFFFFFFFFu - (unsigned int)(key & 0xFFFFFFFFu);
      int box = (int)(idx / NCLS);
      int l   = (int)(idx % NCLS);
      lab[tid] = l;
      int lvl, gx, gy, anc; float stride;
      const float* ptr = locate(img, box, p0, p1, p2, lvl, gx, gy, anc, stride);
      float sx = ref_sigmoid(ptr[0]);
      float sy = ref_sigmoid(ptr[1]);
      float sw = ref_sigmoid(ptr[2]);
      float sh = ref_sigmoid(ptr[3]);
      float aw = anchors[(lvl * 3 + anc) * 2 + 0];
      float ah = anchors[(lvl * 3 + anc) * 2 + 1];
      float cx = (2.0f * sx - 0.5f + (float)gx) * stride;
      float cy = (2.0f * sy - 0.5f + (float)gy) * stride;
      float ww = (4.0f * (sw * sw)) * aw;
      float hh = (4.0f * (sh * sh)) * ah;
      bxs[tid][0] = clip640(cx - ww * 0.5f);
      bxs[tid][1] = clip640(cy - hh * 0.5f);
      bxs[tid][2] = clip640(cx + ww * 0.5f);
      bxs[tid][3] = clip640(cy + hh * 0.5f);
    } else {
      lab[tid] = -1;
      bxs[tid][0] = bxs[tid][1] = bxs[tid][2] = bxs[tid][3] = 0.0f;
    }
  }
  __syncthreads();
  if (tid >= 64) return;

  // wave-0 NMS: lane l owns entries [l*16, l*16+16)
  const int l = tid;
  const float scf = scalef[img];
  unsigned int amask = 0u;
  #pragma unroll
  for (int k = 0; k < 16; ++k) {
    int t = l * 16 + k;
    if (t < NTOP && val[t] > 0.0f) amask |= (1u << k);
  }

  for (int i = 0; i < NDET; ++i) {
    unsigned long long bal = __ballot(amask != 0u);
    float* orow = out + ((size_t)img * NDET + i) * 6;
    if (bal == 0ull) {
      if (l == 0) {
        orow[0] = 0.0f; orow[1] = 0.0f; orow[2] = 0.0f;
        orow[3] = 0.0f; orow[4] = 0.0f; orow[5] = -1.0f;
      }
      continue;
    }
    int L = __ffsll((unsigned long long)bal) - 1;
    unsigned int mL = (unsigned int)__shfl((int)amask, L);
    int j = L * 16 + (__ffs(mL) - 1);

    float b0 = bxs[j][0], b1 = bxs[j][1], b2 = bxs[j][2], b3 = bxs[j][3];
    int lj = lab[j];
    if (l == 0) {
      orow[0] = b0 / scf; orow[1] = b1 / scf;
      orow[2] = b2 / scf; orow[3] = b3 / scf;
      orow[4] = val[j];
      orow[5] = (float)lj;
    }
    float off = (float)lj * 4096.0f;
    float a0 = b0 + off, a1 = b1 + off, a2 = b2 + off, a3 = b3 + off;
    float areaA = (a2 - a0) * (a3 - a1);
    #pragma unroll
    for (int k = 0; k < 16; ++k) {
      if (!((amask >> k) & 1u)) continue;
      int t = l * 16 + k;
      if (lab[t] != lj) continue;               // cross-class IoU exactly 0 in ref
      float o0 = bxs[t][0] + off, o1 = bxs[t][1] + off;
      float o2 = bxs[t][2] + off, o3 = bxs[t][3] + off;
      float ltx = fmaxf(a0, o0);
      float lty = fmaxf(a1, o1);
      float rbx = fminf(a2, o2);
      float rby = fminf(a3, o3);
      float wx = fmaxf(rbx - ltx, 0.0f);
      float wy = fmaxf(rby - lty, 0.0f);
      float inter = wx * wy;
      float a2r = (o2 - o0) * (o3 - o1);
      float denom = areaA + a2r - inter + 1e-7f;
      float iou = inter / denom;
      if (iou > 0.45f) amask &= ~(1u << k);     // includes t==j (ref self-suppression quirk)
    }
  }
}

// ---------------- launcher ----------------
extern "C" void kernel_launch(void* const* d_in, const int* in_sizes, int n_in,
                              void* d_out, int out_size, void* d_ws, size_t ws_size,
                              hipStream_t stream) {
  const float* p0 = (const float*)d_in[0];
  const float* p1 = (const float*)d_in[1];
  const float* p2 = (const float*)d_in[2];
  const float* anchors = (const float*)d_in[3];
  const float* scalef  = (const float*)d_in[4];
  float* out = (float*)d_out;

  char* w = (char*)d_ws;
  // layout: ghist (262144) | cnt (64) | cand (524288) | maxbin (806400)  = ~1.55 MB
  unsigned int* ghist = (unsigned int*)(w);
  int* cnt = (int*)(w + 262144);
  unsigned long long* cand = (unsigned long long*)(w + 262208);
  unsigned short* maxbin = (unsigned short*)(w + 262208 + 524288);

  hipMemsetAsync(ghist, 0, 262144 + 64, stream);   // hist + cnt

  k_passA<<<dim3(NIMG * TILES), dim3(256), 0, stream>>>(p0, p1, p2, ghist, maxbin);
  k_passB<<<dim3(NIMG), dim3(256), 0, stream>>>(p0, p1, p2, ghist, maxbin, cand, cnt);
  k_sortnms<<<dim3(NIMG), dim3(1024), 0, stream>>>(p0, p1, p2, anchors, cand, cnt, scalef, out);
}

// Round 3
// 536.654 us; speedup vs baseline: 4.9927x; 4.9927x over previous
//
#include <hip/hip_runtime.h>
#include <cstdint>
#include <cstddef>

#pragma clang fp contract(off)

constexpr int NIMG  = 16;
constexpr int NB0   = 19200;   // 80*80*3
constexpr int NB1   = 4800;    // 40*40*3
constexpr int NB2   = 1200;    // 20*20*3
constexpr int NBOX  = 25200;
constexpr int NCLS  = 80;
constexpr int NCH   = 85;
constexpr int NBINS = 4096;
constexpr int CAP   = 4096;
constexpr int NTOP  = 1000;
constexpr int NDET  = 100;
constexpr int WLCAP = 65536;   // worklist capacity (<= NIMG*CAP)
constexpr float IMGSZ = 640.0f;
constexpr float BIN_SCALE = 4096.0f / 0.75f;

constexpr int CHUNK   = 64;            // boxes per LDS chunk
constexpr int CHUNK_F = CHUNK * NCH;   // 5440 floats
constexpr int TILE    = 512;           // boxes per block (8 chunks)
constexpr int TILES   = (NBOX + TILE - 1) / TILE;   // 50

// ---------------- XLA-CPU-matching transcendentals (verified absmax=0) ----------------
__device__ __forceinline__ float xla_expf(float x) {
  const float kLog2e = 1.44269504088896341f;
  const float kC1 = 0.693359375f;
  const float kC2 = -2.12194440e-4f;
  const float cp0 = 1.9875691500e-4f;
  const float cp1 = 1.3981999507e-3f;
  const float cp2 = 8.3334519073e-3f;
  const float cp3 = 4.1665795894e-2f;
  const float cp4 = 1.6666665459e-1f;
  const float cp5 = 5.0000001201e-1f;
  float xc = fminf(x, 88.3762626647950f);
  xc = fmaxf(xc, -88.3762626647949f);
  float fx = floorf(fmaf(xc, kLog2e, 0.5f));
  float xr = fmaf(fx, -kC1, xc);
  xr = fmaf(fx, -kC2, xr);
  float z = xr * xr;
  float y = fmaf(cp0, xr, cp1);
  y = fmaf(y, xr, cp2);
  y = fmaf(y, xr, cp3);
  y = fmaf(y, xr, cp4);
  y = fmaf(y, xr, cp5);
  y = fmaf(y, z, xr);
  y = y + 1.0f;
  int n = (int)fx;
  float two_n = __int_as_float((n + 127) << 23);
  float r = y * two_n;
  return fmaxf(r, xc);
}

__device__ __forceinline__ float ref_sigmoid(float x) {
  return 1.0f / (1.0f + xla_expf(-x));
}

// ---------------- geometry helpers ----------------
__device__ __forceinline__ const float* locate(int img, int box,
    const float* __restrict__ p0, const float* __restrict__ p1, const float* __restrict__ p2,
    int& lvl, int& gx, int& gy, int& anc, float& stride) {
  const float* base; int r, W;
  if (box < NB0)            { lvl = 0; r = box;             W = 80; base = p0 + (size_t)img * NB0 * NCH; stride = 8.0f;  }
  else if (box < NB0 + NB1) { lvl = 1; r = box - NB0;       W = 40; base = p1 + (size_t)img * NB1 * NCH; stride = 16.0f; }
  else                      { lvl = 2; r = box - NB0 - NB1; W = 20; base = p2 + (size_t)img * NB2 * NCH; stride = 32.0f; }
  anc = r % 3;
  int cell = r / 3;
  gx = cell % W;
  gy = cell / W;
  return base + (size_t)r * NCH;
}

__device__ __forceinline__ float clip640(float v) {
  return fminf(fmaxf(v, 0.0f), IMGSZ);
}

// chunk (64 aligned boxes) never straddles a level boundary: 19200, 24000 are multiples of 64
__device__ __forceinline__ const float* chunk_ptr(int img, int first_box,
    const float* __restrict__ p0, const float* __restrict__ p1, const float* __restrict__ p2) {
  const float* base; int r;
  if (first_box < NB0)            { base = p0 + (size_t)img * NB0 * NCH; r = first_box; }
  else if (first_box < NB0 + NB1) { base = p1 + (size_t)img * NB1 * NCH; r = first_box - NB0; }
  else                            { base = p2 + (size_t)img * NB2 * NCH; r = first_box - NB0 - NB1; }
  return base + (size_t)r * NCH;
}

// ---------------- pass A: stream input once, histogram + per-box maxbin ----------------
__global__ __launch_bounds__(256) void k_passA(const float* __restrict__ p0,
    const float* __restrict__ p1, const float* __restrict__ p2,
    unsigned int* __restrict__ ghist, unsigned short* __restrict__ maxbin) {
  __shared__ __align__(16) float buf[2][CHUNK_F];
  __shared__ unsigned int hist[NBINS];
  const int tid = threadIdx.x;
  const int img  = blockIdx.x / TILES;
  const int tile = blockIdx.x % TILES;
  const int tbase = tile * TILE;
  const int nbox_tile = min(TILE, NBOX - tbase);
  const int nch = (nbox_tile + CHUNK - 1) / CHUNK;

  for (int i = tid; i < NBINS; i += 256) hist[i] = 0u;

  float4 regs[6];
  // prologue: load chunk 0 into buf[0]
  {
    int nb0c = min(CHUNK, nbox_tile);
    const float* cp = chunk_ptr(img, tbase, p0, p1, p2);
    int nv = (nb0c * NCH) / 4;
    const float4* cp4 = (const float4*)cp;
    float4* b4 = (float4*)&buf[0][0];
    #pragma unroll
    for (int k = 0; k < 6; ++k) { int i = tid + k * 256; if (i < nv) regs[k] = cp4[i]; }
    #pragma unroll
    for (int k = 0; k < 6; ++k) { int i = tid + k * 256; if (i < nv) b4[i] = regs[k]; }
  }
  __syncthreads();

  for (int c = 0; c < nch; ++c) {
    int nvN = 0;
    if (c + 1 < nch) {
      int fb = tbase + (c + 1) * CHUNK;
      int nbN = min(CHUNK, NBOX - fb);
      const float* cp = chunk_ptr(img, fb, p0, p1, p2);
      nvN = (nbN * NCH) / 4;
      const float4* cp4 = (const float4*)cp;
      #pragma unroll
      for (int k = 0; k < 6; ++k) { int i = tid + k * 256; if (i < nvN) regs[k] = cp4[i]; }
    }
    {
      int nb = min(CHUNK, nbox_tile - c * CHUNK);
      int b = tid >> 2, part = tid & 3;
      if (b < nb) {
        const float* row = &buf[c & 1][b * NCH];
        float obj = ref_sigmoid(row[4]);
        int mb = 0;
        if (obj > 0.25f) {
          float rr = 0.25f / obj;
          float tcons = __logf(rr / (1.0f - rr)) - 0.01f;   // conservative pre-filter
          const float* cls = row + 5 + part * 20;
          #pragma unroll 4
          for (int cc = 0; cc < 20; ++cc) {
            float x = cls[cc];
            if (x > tcons) {
              float s = obj * ref_sigmoid(x);               // exact path
              if (s > 0.25f) {
                int bin = (int)((s - 0.25f) * BIN_SCALE);
                bin = min(bin, NBINS - 1);
                atomicAdd(&hist[bin], 1u);
                mb = max(mb, bin + 1);                      // stored = maxbin+1, 0 = none
              }
            }
          }
        }
        mb = max(mb, __shfl_xor(mb, 1, 4));
        mb = max(mb, __shfl_xor(mb, 2, 4));
        if (part == 0)
          maxbin[(size_t)img * NBOX + tbase + c * CHUNK + b] = (unsigned short)mb;
      }
    }
    if (c + 1 < nch) {
      float4* b4 = (float4*)&buf[(c + 1) & 1][0];
      #pragma unroll
      for (int k = 0; k < 6; ++k) { int i = tid + k * 256; if (i < nvN) b4[i] = regs[k]; }
    }
    __syncthreads();
  }

  for (int i = tid; i < NBINS; i += 256) {
    unsigned int v = hist[i];
    if (v) atomicAdd(&ghist[img * NBINS + i], v);
  }
}

// ---------------- per-image threshold bin (parallel scan, 16 blocks) ----------------
__global__ __launch_bounds__(256) void k_thresh(const unsigned int* __restrict__ ghist,
                                                int* __restrict__ tbin) {
  __shared__ unsigned int h[NBINS];
  __shared__ unsigned int psum[256];
  const int tid = threadIdx.x;
  const int img = blockIdx.x;

  for (int i = tid; i < NBINS; i += 256) h[i] = ghist[img * NBINS + i];
  __syncthreads();
  unsigned int ps = 0;
  for (int k = 0; k < 16; ++k) ps += h[tid * 16 + k];
  psum[tid] = ps;
  __syncthreads();
  if (tid == 0) {
    long long cum = 0;
    int tb = 0;
    bool found = false;
    for (int g = 255; g >= 0 && !found; --g) {
      if (cum + (long long)psum[g] >= NTOP) {
        for (int b = g * 16 + 15; b >= g * 16; --b) {
          cum += h[b];
          if (cum >= NTOP) { tb = b; found = true; break; }
        }
      } else {
        cum += psum[g];
      }
    }
    if (!found) tb = 0;
    while (cum > CAP && tb < NBINS - 1) { cum -= h[tb]; ++tb; }
    tbin[img] = tb;
  }
}

// ---------------- worklist: compact passing rows (dense, coalesced) ----------------
__global__ __launch_bounds__(256) void k_worklist(const unsigned short* __restrict__ maxbin,
    const int* __restrict__ tbin, unsigned int* __restrict__ worklist,
    int* __restrict__ wcnt) {
  __shared__ int lcnt;
  __shared__ int lbase;
  const int tid = threadIdx.x;
  if (tid == 0) lcnt = 0;
  __syncthreads();
  int idx = blockIdx.x * 256 + tid;
  bool pass = false;
  int my = 0;
  int img = 0, box = 0;
  if (idx < NIMG * NBOX) {
    img = idx / NBOX;
    box = idx - img * NBOX;
    int mb = (int)maxbin[idx];
    if (mb > tbin[img]) {            // mb = maxbin+1 > tb  <=>  maxbin >= tb
      pass = true;
      my = atomicAdd(&lcnt, 1);
    }
  }
  __syncthreads();
  if (tid == 0 && lcnt > 0) lbase = atomicAdd(wcnt, lcnt);
  __syncthreads();
  if (pass) {
    int pos = lbase + my;
    if (pos < WLCAP) worklist[pos] = ((unsigned int)img << 16) | (unsigned int)box;
  }
}

// ---------------- emit: one dense row per thread, exact keys ----------------
__global__ __launch_bounds__(256) void k_emit(const float* __restrict__ p0,
    const float* __restrict__ p1, const float* __restrict__ p2,
    const unsigned int* __restrict__ worklist, const int* __restrict__ wcnt,
    const int* __restrict__ tbin, unsigned long long* __restrict__ cand,
    int* __restrict__ cnt) {
  int n = *wcnt;
  if (n > WLCAP) n = WLCAP;
  const int nthreads = gridDim.x * 256;
  for (int i = blockIdx.x * 256 + threadIdx.x; i < n; i += nthreads) {
    unsigned int e = worklist[i];
    int img = (int)(e >> 16);
    int box = (int)(e & 0xFFFFu);
    int lvl, gx, gy, anc; float stride;
    const float* ptr = locate(img, box, p0, p1, p2, lvl, gx, gy, anc, stride);
    float obj = ref_sigmoid(ptr[4]);
    if (obj <= 0.25f) continue;
    int tb = tbin[img];
    float rr = 0.25f / obj;
    float tcons = __logf(rr / (1.0f - rr)) - 0.01f;
    #pragma unroll 8
    for (int c = 0; c < NCLS; ++c) {
      float x = ptr[5 + c];
      if (x <= tcons) continue;
      float s = obj * ref_sigmoid(x);
      if (s > 0.25f) {
        int bin = (int)((s - 0.25f) * BIN_SCALE);
        bin = min(bin, NBINS - 1);
        if (bin >= tb) {
          int pos = atomicAdd(&cnt[img], 1);
          if (pos < CAP) {
            unsigned int fi = (unsigned int)(box * NCLS + c);
            unsigned long long key =
                ((unsigned long long)__float_as_uint(s) << 32) |
                (unsigned long long)(0xFFFFFFFFu - fi);
            cand[(size_t)img * CAP + pos] = key;
          }
        }
      }
    }
  }
}

// ---------------- fused sort + NMS (one block per image) ----------------
__global__ __launch_bounds__(1024) void k_sortnms(const float* __restrict__ p0,
    const float* __restrict__ p1, const float* __restrict__ p2,
    const float* __restrict__ anchors, const unsigned long long* __restrict__ cand,
    const int* __restrict__ cnt_arr, const float* __restrict__ scalef,
    float* __restrict__ out) {
  __shared__ unsigned long long keys[CAP];   // 32 KB
  __shared__ float bxs[NTOP][4];             // 16 KB
  __shared__ float val[NTOP];                //  4 KB
  __shared__ int   lab[NTOP];                //  4 KB
  __shared__ int   n2_sh, cnt_sh;
  const int tid = threadIdx.x;
  const int img = blockIdx.x;

  if (tid == 0) {
    int c = cnt_arr[img];
    c = max(0, min(c, CAP));
    int n2 = 1024;
    while (n2 < c) n2 <<= 1;
    cnt_sh = c; n2_sh = n2;
  }
  __syncthreads();
  const int cnt = cnt_sh;
  const int n2  = n2_sh;

  const unsigned long long* c = cand + (size_t)img * CAP;
  for (int i = tid; i < n2; i += 1024) keys[i] = (i < cnt) ? c[i] : 0ull;
  __syncthreads();

  for (int kk = 2; kk <= n2; kk <<= 1) {
    for (int j = kk >> 1; j > 0; j >>= 1) {
      for (int i = tid; i < n2; i += 1024) {
        int l = i ^ j;
        if (l > i) {
          unsigned long long a = keys[i], b = keys[l];
          bool up = ((i & kk) == 0);
          bool sw = up ? (a < b) : (a > b);
          if (sw) { keys[i] = b; keys[l] = a; }
        }
      }
      __syncthreads();
    }
  }

  // decode top-1000
  if (tid < NTOP) {
    unsigned long long key = keys[tid];
    unsigned int v = (unsigned int)(key >> 32);
    val[tid] = __uint_as_float(v);
    if (v) {
      unsigned int idx = 0xFFFFFFFFu - (unsigned int)(key & 0xFFFFFFFFu);
      int box = (int)(idx / NCLS);
      int l   = (int)(idx % NCLS);
      lab[tid] = l;
      int lvl, gx, gy, anc; float stride;
      const float* ptr = locate(img, box, p0, p1, p2, lvl, gx, gy, anc, stride);
      float sx = ref_sigmoid(ptr[0]);
      float sy = ref_sigmoid(ptr[1]);
      float sw = ref_sigmoid(ptr[2]);
      float sh = ref_sigmoid(ptr[3]);
      float aw = anchors[(lvl * 3 + anc) * 2 + 0];
      float ah = anchors[(lvl * 3 + anc) * 2 + 1];
      float cx = (2.0f * sx - 0.5f + (float)gx) * stride;
      float cy = (2.0f * sy - 0.5f + (float)gy) * stride;
      float ww = (4.0f * (sw * sw)) * aw;
      float hh = (4.0f * (sh * sh)) * ah;
      bxs[tid][0] = clip640(cx - ww * 0.5f);
      bxs[tid][1] = clip640(cy - hh * 0.5f);
      bxs[tid][2] = clip640(cx + ww * 0.5f);
      bxs[tid][3] = clip640(cy + hh * 0.5f);
    } else {
      lab[tid] = -1;
      bxs[tid][0] = bxs[tid][1] = bxs[tid][2] = bxs[tid][3] = 0.0f;
    }
  }
  __syncthreads();
  if (tid >= 64) return;

  // wave-0 NMS: lane l owns entries [l*16, l*16+16)
  const int l = tid;
  const float scf = scalef[img];
  unsigned int amask = 0u;
  #pragma unroll
  for (int k = 0; k < 16; ++k) {
    int t = l * 16 + k;
    if (t < NTOP && val[t] > 0.0f) amask |= (1u << k);
  }

  for (int i = 0; i < NDET; ++i) {
    unsigned long long bal = __ballot(amask != 0u);
    float* orow = out + ((size_t)img * NDET + i) * 6;
    if (bal == 0ull) {
      if (l == 0) {
        orow[0] = 0.0f; orow[1] = 0.0f; orow[2] = 0.0f;
        orow[3] = 0.0f; orow[4] = 0.0f; orow[5] = -1.0f;
      }
      continue;
    }
    int L = __ffsll((unsigned long long)bal) - 1;
    unsigned int mL = (unsigned int)__shfl((int)amask, L);
    int j = L * 16 + (__ffs(mL) - 1);

    float b0 = bxs[j][0], b1 = bxs[j][1], b2 = bxs[j][2], b3 = bxs[j][3];
    int lj = lab[j];
    if (l == 0) {
      orow[0] = b0 / scf; orow[1] = b1 / scf;
      orow[2] = b2 / scf; orow[3] = b3 / scf;
      orow[4] = val[j];
      orow[5] = (float)lj;
    }
    float off = (float)lj * 4096.0f;
    float a0 = b0 + off, a1 = b1 + off, a2 = b2 + off, a3 = b3 + off;
    float areaA = (a2 - a0) * (a3 - a1);
    #pragma unroll
    for (int k = 0; k < 16; ++k) {
      if (!((amask >> k) & 1u)) continue;
      int t = l * 16 + k;
      if (lab[t] != lj) continue;               // cross-class IoU exactly 0 in ref
      float o0 = bxs[t][0] + off, o1 = bxs[t][1] + off;
      float o2 = bxs[t][2] + off, o3 = bxs[t][3] + off;
      float ltx = fmaxf(a0, o0);
      float lty = fmaxf(a1, o1);
      float rbx = fminf(a2, o2);
      float rby = fminf(a3, o3);
      float wx = fmaxf(rbx - ltx, 0.0f);
      float wy = fmaxf(rby - lty, 0.0f);
      float inter = wx * wy;
      float a2r = (o2 - o0) * (o3 - o1);
      float denom = areaA + a2r - inter + 1e-7f;
      float iou = inter / denom;
      if (iou > 0.45f) amask &= ~(1u << k);     // includes t==j (ref self-suppression quirk)
    }
  }
}

// ---------------- launcher ----------------
extern "C" void kernel_launch(void* const* d_in, const int* in_sizes, int n_in,
                              void* d_out, int out_size, void* d_ws, size_t ws_size,
                              hipStream_t stream) {
  const float* p0 = (const float*)d_in[0];
  const float* p1 = (const float*)d_in[1];
  const float* p2 = (const float*)d_in[2];
  const float* anchors = (const float*)d_in[3];
  const float* scalef  = (const float*)d_in[4];
  float* out = (float*)d_out;

  char* w = (char*)d_ws;
  // layout (bytes): ghist 262144 | cnt 64 | tbin 64 | wcnt 64 | cand 524288 |
  //                 maxbin 806400 | worklist 262144   (~1.86 MB)
  unsigned int* ghist = (unsigned int*)(w);
  int* cnt  = (int*)(w + 262144);
  int* tbin = (int*)(w + 262208);
  int* wcnt = (int*)(w + 262272);
  unsigned long long* cand = (unsigned long long*)(w + 262336);
  unsigned short* maxbin = (unsigned short*)(w + 262336 + 524288);       // 786624
  unsigned int* worklist = (unsigned int*)(w + 786624 + 806400);         // 1593024

  hipMemsetAsync(ghist, 0, 262144 + 192, stream);   // hist + cnt + tbin + wcnt

  k_passA<<<dim3(NIMG * TILES), dim3(256), 0, stream>>>(p0, p1, p2, ghist, maxbin);
  k_thresh<<<dim3(NIMG), dim3(256), 0, stream>>>(ghist, tbin);
  k_worklist<<<dim3((NIMG * NBOX + 255) / 256), dim3(256), 0, stream>>>(maxbin, tbin, worklist, wcnt);
  k_emit<<<dim3(256), dim3(256), 0, stream>>>(p0, p1, p2, worklist, wcnt, tbin, cand, cnt);
  k_sortnms<<<dim3(NIMG), dim3(1024), 0, stream>>>(p0, p1, p2, anchors, cand, cnt, scalef, out);
}

// Round 4
// 421.091 us; speedup vs baseline: 6.3629x; 1.2744x over previous
//
#include <hip/hip_runtime.h>
#include <cstdint>
#include <cstddef>

#pragma clang fp contract(off)

constexpr int NIMG  = 16;
constexpr int NB0   = 19200;   // 80*80*3
constexpr int NB1   = 4800;    // 40*40*3
constexpr int NB2   = 1200;    // 20*20*3
constexpr int NBOX  = 25200;
constexpr int NCLS  = 80;
constexpr int NCH   = 85;
constexpr int NBINS = 4096;
constexpr int CAP   = 4096;
constexpr int NTOP  = 1000;
constexpr int NDET  = 100;
constexpr int WLCAP = 65536;   // worklist capacity (<= NIMG*CAP)
constexpr float IMGSZ = 640.0f;
constexpr float BIN_SCALE = 4096.0f / 0.75f;

constexpr int CHUNK   = 64;            // boxes per LDS chunk
constexpr int CHUNK_F = CHUNK * NCH;   // 5440 floats
constexpr int TILE    = 512;           // boxes per block (8 chunks)
constexpr int TILES   = (NBOX + TILE - 1) / TILE;   // 50

// ---------------- XLA-CPU-matching transcendentals (verified absmax=0) ----------------
__device__ __forceinline__ float xla_expf(float x) {
  const float kLog2e = 1.44269504088896341f;
  const float kC1 = 0.693359375f;
  const float kC2 = -2.12194440e-4f;
  const float cp0 = 1.9875691500e-4f;
  const float cp1 = 1.3981999507e-3f;
  const float cp2 = 8.3334519073e-3f;
  const float cp3 = 4.1665795894e-2f;
  const float cp4 = 1.6666665459e-1f;
  const float cp5 = 5.0000001201e-1f;
  float xc = fminf(x, 88.3762626647950f);
  xc = fmaxf(xc, -88.3762626647949f);
  float fx = floorf(fmaf(xc, kLog2e, 0.5f));
  float xr = fmaf(fx, -kC1, xc);
  xr = fmaf(fx, -kC2, xr);
  float z = xr * xr;
  float y = fmaf(cp0, xr, cp1);
  y = fmaf(y, xr, cp2);
  y = fmaf(y, xr, cp3);
  y = fmaf(y, xr, cp4);
  y = fmaf(y, xr, cp5);
  y = fmaf(y, z, xr);
  y = y + 1.0f;
  int n = (int)fx;
  float two_n = __int_as_float((n + 127) << 23);
  float r = y * two_n;
  return fmaxf(r, xc);
}

__device__ __forceinline__ float ref_sigmoid(float x) {
  return 1.0f / (1.0f + xla_expf(-x));
}

// ---------------- geometry helpers ----------------
__device__ __forceinline__ const float* locate(int img, int box,
    const float* __restrict__ p0, const float* __restrict__ p1, const float* __restrict__ p2,
    int& lvl, int& gx, int& gy, int& anc, float& stride) {
  const float* base; int r, W;
  if (box < NB0)            { lvl = 0; r = box;             W = 80; base = p0 + (size_t)img * NB0 * NCH; stride = 8.0f;  }
  else if (box < NB0 + NB1) { lvl = 1; r = box - NB0;       W = 40; base = p1 + (size_t)img * NB1 * NCH; stride = 16.0f; }
  else                      { lvl = 2; r = box - NB0 - NB1; W = 20; base = p2 + (size_t)img * NB2 * NCH; stride = 32.0f; }
  anc = r % 3;
  int cell = r / 3;
  gx = cell % W;
  gy = cell / W;
  return base + (size_t)r * NCH;
}

__device__ __forceinline__ float clip640(float v) {
  return fminf(fmaxf(v, 0.0f), IMGSZ);
}

// chunk (64 aligned boxes) never straddles a level boundary: 19200, 24000 are multiples of 64
__device__ __forceinline__ const float* chunk_ptr(int img, int first_box,
    const float* __restrict__ p0, const float* __restrict__ p1, const float* __restrict__ p2) {
  const float* base; int r;
  if (first_box < NB0)            { base = p0 + (size_t)img * NB0 * NCH; r = first_box; }
  else if (first_box < NB0 + NB1) { base = p1 + (size_t)img * NB1 * NCH; r = first_box - NB0; }
  else                            { base = p2 + (size_t)img * NB2 * NCH; r = first_box - NB0 - NB1; }
  return base + (size_t)r * NCH;
}

// ---------------- pass A: stream input once, histogram + per-box maxbin ----------------
__global__ __launch_bounds__(256) void k_passA(const float* __restrict__ p0,
    const float* __restrict__ p1, const float* __restrict__ p2,
    unsigned int* __restrict__ ghist, unsigned short* __restrict__ maxbin) {
  __shared__ __align__(16) float buf[2][CHUNK_F];
  __shared__ unsigned int hist[NBINS];
  const int tid = threadIdx.x;
  const int img  = blockIdx.x / TILES;
  const int tile = blockIdx.x % TILES;
  const int tbase = tile * TILE;
  const int nbox_tile = min(TILE, NBOX - tbase);
  const int nch = (nbox_tile + CHUNK - 1) / CHUNK;

  for (int i = tid; i < NBINS; i += 256) hist[i] = 0u;

  float4 regs[6];
  // prologue: load chunk 0 into buf[0]
  {
    int nb0c = min(CHUNK, nbox_tile);
    const float* cp = chunk_ptr(img, tbase, p0, p1, p2);
    int nv = (nb0c * NCH) / 4;
    const float4* cp4 = (const float4*)cp;
    float4* b4 = (float4*)&buf[0][0];
    #pragma unroll
    for (int k = 0; k < 6; ++k) { int i = tid + k * 256; if (i < nv) regs[k] = cp4[i]; }
    #pragma unroll
    for (int k = 0; k < 6; ++k) { int i = tid + k * 256; if (i < nv) b4[i] = regs[k]; }
  }
  __syncthreads();

  for (int c = 0; c < nch; ++c) {
    int nvN = 0;
    if (c + 1 < nch) {
      int fb = tbase + (c + 1) * CHUNK;
      int nbN = min(CHUNK, NBOX - fb);
      const float* cp = chunk_ptr(img, fb, p0, p1, p2);
      nvN = (nbN * NCH) / 4;
      const float4* cp4 = (const float4*)cp;
      #pragma unroll
      for (int k = 0; k < 6; ++k) { int i = tid + k * 256; if (i < nvN) regs[k] = cp4[i]; }
    }
    {
      int nb = min(CHUNK, nbox_tile - c * CHUNK);
      int b = tid >> 2, part = tid & 3;
      if (b < nb) {
        const float* row = &buf[c & 1][b * NCH];
        float obj = ref_sigmoid(row[4]);
        int mb = 0;
        if (obj > 0.25f) {
          float rr = 0.25f / obj;
          float tcons = __logf(rr / (1.0f - rr)) - 0.01f;   // conservative pre-filter
          const float* cls = row + 5 + part * 20;
          #pragma unroll 4
          for (int cc = 0; cc < 20; ++cc) {
            float x = cls[cc];
            if (x > tcons) {
              float s = obj * ref_sigmoid(x);               // exact path
              if (s > 0.25f) {
                int bin = (int)((s - 0.25f) * BIN_SCALE);
                bin = min(bin, NBINS - 1);
                atomicAdd(&hist[bin], 1u);
                mb = max(mb, bin + 1);                      // stored = maxbin+1, 0 = none
              }
            }
          }
        }
        mb = max(mb, __shfl_xor(mb, 1, 4));
        mb = max(mb, __shfl_xor(mb, 2, 4));
        if (part == 0)
          maxbin[(size_t)img * NBOX + tbase + c * CHUNK + b] = (unsigned short)mb;
      }
    }
    if (c + 1 < nch) {
      float4* b4 = (float4*)&buf[(c + 1) & 1][0];
      #pragma unroll
      for (int k = 0; k < 6; ++k) { int i = tid + k * 256; if (i < nvN) b4[i] = regs[k]; }
    }
    __syncthreads();
  }

  for (int i = tid; i < NBINS; i += 256) {
    unsigned int v = hist[i];
    if (v) atomicAdd(&ghist[img * NBINS + i], v);
  }
}

// ---------------- per-image threshold bin (parallel scan, 16 blocks) ----------------
__global__ __launch_bounds__(256) void k_thresh(const unsigned int* __restrict__ ghist,
                                                int* __restrict__ tbin) {
  __shared__ unsigned int h[NBINS];
  __shared__ unsigned int psum[256];
  const int tid = threadIdx.x;
  const int img = blockIdx.x;

  for (int i = tid; i < NBINS; i += 256) h[i] = ghist[img * NBINS + i];
  __syncthreads();
  unsigned int ps = 0;
  for (int k = 0; k < 16; ++k) ps += h[tid * 16 + k];
  psum[tid] = ps;
  __syncthreads();
  if (tid == 0) {
    long long cum = 0;
    int tb = 0;
    bool found = false;
    for (int g = 255; g >= 0 && !found; --g) {
      if (cum + (long long)psum[g] >= NTOP) {
        for (int b = g * 16 + 15; b >= g * 16; --b) {
          cum += h[b];
          if (cum >= NTOP) { tb = b; found = true; break; }
        }
      } else {
        cum += psum[g];
      }
    }
    if (!found) tb = 0;
    while (cum > CAP && tb < NBINS - 1) { cum -= h[tb]; ++tb; }
    tbin[img] = tb;
  }
}

// ---------------- worklist: compact passing rows (dense, coalesced) ----------------
__global__ __launch_bounds__(256) void k_worklist(const unsigned short* __restrict__ maxbin,
    const int* __restrict__ tbin, unsigned int* __restrict__ worklist,
    int* __restrict__ wcnt) {
  __shared__ int lcnt;
  __shared__ int lbase;
  const int tid = threadIdx.x;
  if (tid == 0) lcnt = 0;
  __syncthreads();
  int idx = blockIdx.x * 256 + tid;
  bool pass = false;
  int my = 0;
  int img = 0, box = 0;
  if (idx < NIMG * NBOX) {
    img = idx / NBOX;
    box = idx - img * NBOX;
    int mb = (int)maxbin[idx];
    if (mb > tbin[img]) {            // mb = maxbin+1 > tb  <=>  maxbin >= tb
      pass = true;
      my = atomicAdd(&lcnt, 1);
    }
  }
  __syncthreads();
  if (tid == 0 && lcnt > 0) lbase = atomicAdd(wcnt, lcnt);
  __syncthreads();
  if (pass) {
    int pos = lbase + my;
    if (pos < WLCAP) worklist[pos] = ((unsigned int)img << 16) | (unsigned int)box;
  }
}

// ---------------- emit: one dense row per thread, exact keys ----------------
__global__ __launch_bounds__(256) void k_emit(const float* __restrict__ p0,
    const float* __restrict__ p1, const float* __restrict__ p2,
    const unsigned int* __restrict__ worklist, const int* __restrict__ wcnt,
    const int* __restrict__ tbin, unsigned long long* __restrict__ cand,
    int* __restrict__ cnt) {
  int n = *wcnt;
  if (n > WLCAP) n = WLCAP;
  const int nthreads = gridDim.x * 256;
  for (int i = blockIdx.x * 256 + threadIdx.x; i < n; i += nthreads) {
    unsigned int e = worklist[i];
    int img = (int)(e >> 16);
    int box = (int)(e & 0xFFFFu);
    int lvl, gx, gy, anc; float stride;
    const float* ptr = locate(img, box, p0, p1, p2, lvl, gx, gy, anc, stride);
    float obj = ref_sigmoid(ptr[4]);
    if (obj <= 0.25f) continue;
    int tb = tbin[img];
    float rr = 0.25f / obj;
    float tcons = __logf(rr / (1.0f - rr)) - 0.01f;
    #pragma unroll 8
    for (int c = 0; c < NCLS; ++c) {
      float x = ptr[5 + c];
      if (x <= tcons) continue;
      float s = obj * ref_sigmoid(x);
      if (s > 0.25f) {
        int bin = (int)((s - 0.25f) * BIN_SCALE);
        bin = min(bin, NBINS - 1);
        if (bin >= tb) {
          int pos = atomicAdd(&cnt[img], 1);
          if (pos < CAP) {
            unsigned int fi = (unsigned int)(box * NCLS + c);
            unsigned long long key =
                ((unsigned long long)__float_as_uint(s) << 32) |
                (unsigned long long)(0xFFFFFFFFu - fi);
            cand[(size_t)img * CAP + pos] = key;
          }
        }
      }
    }
  }
}

// ---------------- fused sort + NMS (one block per image) ----------------
// swizzled LDS index: pad every 16 u64 keys to break the i/i+16 bank aliasing
#define SIDX(i) ((i) + ((i) >> 4))

__global__ __launch_bounds__(1024) void k_sortnms(const float* __restrict__ p0,
    const float* __restrict__ p1, const float* __restrict__ p2,
    const float* __restrict__ anchors, const unsigned long long* __restrict__ cand,
    const int* __restrict__ cnt_arr, const float* __restrict__ scalef,
    float* __restrict__ out) {
  __shared__ unsigned long long keys[CAP + CAP / 16];   // 34.8 KB (swizzled)
  __shared__ float bxs[NTOP][4];             // 16 KB
  __shared__ float val[NTOP];                //  4 KB
  __shared__ int   lab[NTOP];                //  4 KB
  __shared__ int   n2_sh, cnt_sh;
  const int tid = threadIdx.x;
  const int img = blockIdx.x;

  if (tid == 0) {
    int c = cnt_arr[img];
    c = max(0, min(c, CAP));
    int n2 = 1024;
    while (n2 < c) n2 <<= 1;
    cnt_sh = c; n2_sh = n2;
  }
  __syncthreads();
  const int cnt = cnt_sh;
  const int n2  = n2_sh;

  const unsigned long long* c = cand + (size_t)img * CAP;
  for (int i = tid; i < n2; i += 1024) keys[SIDX(i)] = (i < cnt) ? c[i] : 0ull;
  __syncthreads();

  for (int kk = 2; kk <= n2; kk <<= 1) {
    for (int j = kk >> 1; j > 0; j >>= 1) {
      for (int i = tid; i < n2; i += 1024) {
        int l = i ^ j;
        if (l > i) {
          unsigned long long a = keys[SIDX(i)], b = keys[SIDX(l)];
          bool up = ((i & kk) == 0);
          bool sw = up ? (a < b) : (a > b);
          if (sw) { keys[SIDX(i)] = b; keys[SIDX(l)] = a; }
        }
      }
      __syncthreads();
    }
  }

  // decode top-1000
  if (tid < NTOP) {
    unsigned long long key = keys[SIDX(tid)];
    unsigned int v = (unsigned int)(key >> 32);
    val[tid] = __uint_as_float(v);
    if (v) {
      unsigned int idx = 0xFFFFFFFFu - (unsigned int)(key & 0xFFFFFFFFu);
      int box = (int)(idx / NCLS);
      int l   = (int)(idx % NCLS);
      lab[tid] = l;
      int lvl, gx, gy, anc; float stride;
      const float* ptr = locate(img, box, p0, p1, p2, lvl, gx, gy, anc, stride);
      float sx = ref_sigmoid(ptr[0]);
      float sy = ref_sigmoid(ptr[1]);
      float sw = ref_sigmoid(ptr[2]);
      float sh = ref_sigmoid(ptr[3]);
      float aw = anchors[(lvl * 3 + anc) * 2 + 0];
      float ah = anchors[(lvl * 3 + anc) * 2 + 1];
      float cx = (2.0f * sx - 0.5f + (float)gx) * stride;
      float cy = (2.0f * sy - 0.5f + (float)gy) * stride;
      float ww = (4.0f * (sw * sw)) * aw;
      float hh = (4.0f * (sh * sh)) * ah;
      bxs[tid][0] = clip640(cx - ww * 0.5f);
      bxs[tid][1] = clip640(cy - hh * 0.5f);
      bxs[tid][2] = clip640(cx + ww * 0.5f);
      bxs[tid][3] = clip640(cy + hh * 0.5f);
    } else {
      lab[tid] = -1;
      bxs[tid][0] = bxs[tid][1] = bxs[tid][2] = bxs[tid][3] = 0.0f;
    }
  }
  __syncthreads();
  if (tid >= 64) return;

  // wave-0 NMS: lane l owns entries [l*16, l*16+16), box data in REGISTERS
  // (one-time LDS->reg copy; the 100-iteration loop reads LDS only via
  //  same-address broadcasts, eliminating the 64-way bank conflicts)
  const int l = tid;
  const float scf = scalef[img];
  float rb0[16], rb1[16], rb2[16], rb3[16];
  int rlab[16];
  unsigned int amask = 0u;
  #pragma unroll
  for (int k = 0; k < 16; ++k) {
    int t = l * 16 + k;
    if (t < NTOP) {
      rb0[k] = bxs[t][0]; rb1[k] = bxs[t][1];
      rb2[k] = bxs[t][2]; rb3[k] = bxs[t][3];
      rlab[k] = lab[t];
      if (val[t] > 0.0f) amask |= (1u << k);
    } else {
      rb0[k] = rb1[k] = rb2[k] = rb3[k] = 0.0f;
      rlab[k] = -1;
    }
  }

  for (int i = 0; i < NDET; ++i) {
    unsigned long long bal = __ballot(amask != 0u);
    float* orow = out + ((size_t)img * NDET + i) * 6;
    if (bal == 0ull) {
      if (l == 0) {
        orow[0] = 0.0f; orow[1] = 0.0f; orow[2] = 0.0f;
        orow[3] = 0.0f; orow[4] = 0.0f; orow[5] = -1.0f;
      }
      continue;
    }
    int L = __ffsll((unsigned long long)bal) - 1;
    unsigned int mL = (unsigned int)__shfl((int)amask, L);
    int j = L * 16 + (__ffs(mL) - 1);

    // broadcast reads (same address on all lanes -> no conflicts)
    float b0 = bxs[j][0], b1 = bxs[j][1], b2 = bxs[j][2], b3 = bxs[j][3];
    int lj = lab[j];
    if (l == 0) {
      orow[0] = b0 / scf; orow[1] = b1 / scf;
      orow[2] = b2 / scf; orow[3] = b3 / scf;
      orow[4] = val[j];
      orow[5] = (float)lj;
    }
    float off = (float)lj * 4096.0f;
    float a0 = b0 + off, a1 = b1 + off, a2 = b2 + off, a3 = b3 + off;
    float areaA = (a2 - a0) * (a3 - a1);
    #pragma unroll
    for (int k = 0; k < 16; ++k) {
      if (!((amask >> k) & 1u)) continue;
      if (rlab[k] != lj) continue;              // cross-class IoU exactly 0 in ref
      float o0 = rb0[k] + off, o1 = rb1[k] + off;
      float o2 = rb2[k] + off, o3 = rb3[k] + off;
      float ltx = fmaxf(a0, o0);
      float lty = fmaxf(a1, o1);
      float rbx = fminf(a2, o2);
      float rby = fminf(a3, o3);
      float wx = fmaxf(rbx - ltx, 0.0f);
      float wy = fmaxf(rby - lty, 0.0f);
      float inter = wx * wy;
      float a2r = (o2 - o0) * (o3 - o1);
      float denom = areaA + a2r - inter + 1e-7f;
      float iou = inter / denom;
      if (iou > 0.45f) amask &= ~(1u << k);     // includes t==j (ref self-suppression quirk)
    }
  }
}

// ---------------- launcher ----------------
extern "C" void kernel_launch(void* const* d_in, const int* in_sizes, int n_in,
                              void* d_out, int out_size, void* d_ws, size_t ws_size,
                              hipStream_t stream) {
  const float* p0 = (const float*)d_in[0];
  const float* p1 = (const float*)d_in[1];
  const float* p2 = (const float*)d_in[2];
  const float* anchors = (const float*)d_in[3];
  const float* scalef  = (const float*)d_in[4];
  float* out = (float*)d_out;

  char* w = (char*)d_ws;
  // layout (bytes): ghist 262144 | cnt 64 | tbin 64 | wcnt 64 | cand 524288 |
  //                 maxbin 806400 | worklist 262144   (~1.86 MB)
  unsigned int* ghist = (unsigned int*)(w);
  int* cnt  = (int*)(w + 262144);
  int* tbin = (int*)(w + 262208);
  int* wcnt = (int*)(w + 262272);
  unsigned long long* cand = (unsigned long long*)(w + 262336);
  unsigned short* maxbin = (unsigned short*)(w + 262336 + 524288);       // 786624
  unsigned int* worklist = (unsigned int*)(w + 786624 + 806400);         // 1593024

  hipMemsetAsync(ghist, 0, 262144 + 192, stream);   // hist + cnt + tbin + wcnt

  k_passA<<<dim3(NIMG * TILES), dim3(256), 0, stream>>>(p0, p1, p2, ghist, maxbin);
  k_thresh<<<dim3(NIMG), dim3(256), 0, stream>>>(ghist, tbin);
  k_worklist<<<dim3((NIMG * NBOX + 255) / 256), dim3(256), 0, stream>>>(maxbin, tbin, worklist, wcnt);
  k_emit<<<dim3(256), dim3(256), 0, stream>>>(p0, p1, p2, worklist, wcnt, tbin, cand, cnt);
  k_sortnms<<<dim3(NIMG), dim3(1024), 0, stream>>>(p0, p1, p2, anchors, cand, cnt, scalef, out);
}

// Round 5
// 386.740 us; speedup vs baseline: 6.9281x; 1.0888x over previous
//
#include <hip/hip_runtime.h>
#include <cstdint>
#include <cstddef>

#pragma clang fp contract(off)

constexpr int NIMG  = 16;
constexpr int NB0   = 19200;   // 80*80*3
constexpr int NB1   = 4800;    // 40*40*3
constexpr int NB2   = 1200;    // 20*20*3
constexpr int NBOX  = 25200;
constexpr int NCLS  = 80;
constexpr int NCH   = 85;
constexpr int NBINS = 4096;
constexpr int CAP   = 4096;
constexpr int NTOP  = 1000;
constexpr int NDET  = 100;
constexpr int WLCAP = 65536;   // worklist capacity (<= NIMG*CAP)
constexpr float IMGSZ = 640.0f;
constexpr float BIN_SCALE = 4096.0f / 0.75f;

constexpr int CHUNK   = 32;            // boxes per LDS chunk (38 KB total LDS -> 4 blocks/CU)
constexpr int CHUNK_F = CHUNK * NCH;   // 2720 floats
constexpr int TILE    = 512;           // boxes per block (16 chunks)
constexpr int TILES   = (NBOX + TILE - 1) / TILE;   // 50

// ---------------- XLA-CPU-matching transcendentals (verified absmax=0) ----------------
__device__ __forceinline__ float xla_expf(float x) {
  const float kLog2e = 1.44269504088896341f;
  const float kC1 = 0.693359375f;
  const float kC2 = -2.12194440e-4f;
  const float cp0 = 1.9875691500e-4f;
  const float cp1 = 1.3981999507e-3f;
  const float cp2 = 8.3334519073e-3f;
  const float cp3 = 4.1665795894e-2f;
  const float cp4 = 1.6666665459e-1f;
  const float cp5 = 5.0000001201e-1f;
  float xc = fminf(x, 88.3762626647950f);
  xc = fmaxf(xc, -88.3762626647949f);
  float fx = floorf(fmaf(xc, kLog2e, 0.5f));
  float xr = fmaf(fx, -kC1, xc);
  xr = fmaf(fx, -kC2, xr);
  float z = xr * xr;
  float y = fmaf(cp0, xr, cp1);
  y = fmaf(y, xr, cp2);
  y = fmaf(y, xr, cp3);
  y = fmaf(y, xr, cp4);
  y = fmaf(y, xr, cp5);
  y = fmaf(y, z, xr);
  y = y + 1.0f;
  int n = (int)fx;
  float two_n = __int_as_float((n + 127) << 23);
  float r = y * two_n;
  return fmaxf(r, xc);
}

__device__ __forceinline__ float ref_sigmoid(float x) {
  return 1.0f / (1.0f + xla_expf(-x));
}

// ---------------- geometry helpers ----------------
__device__ __forceinline__ const float* locate(int img, int box,
    const float* __restrict__ p0, const float* __restrict__ p1, const float* __restrict__ p2,
    int& lvl, int& gx, int& gy, int& anc, float& stride) {
  const float* base; int r, W;
  if (box < NB0)            { lvl = 0; r = box;             W = 80; base = p0 + (size_t)img * NB0 * NCH; stride = 8.0f;  }
  else if (box < NB0 + NB1) { lvl = 1; r = box - NB0;       W = 40; base = p1 + (size_t)img * NB1 * NCH; stride = 16.0f; }
  else                      { lvl = 2; r = box - NB0 - NB1; W = 20; base = p2 + (size_t)img * NB2 * NCH; stride = 32.0f; }
  anc = r % 3;
  int cell = r / 3;
  gx = cell % W;
  gy = cell / W;
  return base + (size_t)r * NCH;
}

__device__ __forceinline__ float clip640(float v) {
  return fminf(fmaxf(v, 0.0f), IMGSZ);
}

// chunk (32 aligned boxes) never straddles a level boundary: 19200, 24000 are multiples of 32
__device__ __forceinline__ const float* chunk_ptr(int img, int first_box,
    const float* __restrict__ p0, const float* __restrict__ p1, const float* __restrict__ p2) {
  const float* base; int r;
  if (first_box < NB0)            { base = p0 + (size_t)img * NB0 * NCH; r = first_box; }
  else if (first_box < NB0 + NB1) { base = p1 + (size_t)img * NB1 * NCH; r = first_box - NB0; }
  else                            { base = p2 + (size_t)img * NB2 * NCH; r = first_box - NB0 - NB1; }
  return base + (size_t)r * NCH;
}

// ---------------- pass A: stream input once, histogram + per-box maxbin ----------------
// 8 threads/box, 10 interleaved classes each (5 + part + 8*cc): all 256 threads
// active in compute; wave-local LDS conflicts <=3-way (stride-85 rows, 8 boxes/wave).
__global__ __launch_bounds__(256) void k_passA(const float* __restrict__ p0,
    const float* __restrict__ p1, const float* __restrict__ p2,
    unsigned int* __restrict__ ghist, unsigned short* __restrict__ maxbin) {
  __shared__ __align__(16) float buf[2][CHUNK_F];   // 21.76 KB
  __shared__ unsigned int hist[NBINS];              // 16 KB
  const int tid = threadIdx.x;
  const int img  = blockIdx.x / TILES;
  const int tile = blockIdx.x % TILES;
  const int tbase = tile * TILE;
  const int nbox_tile = min(TILE, NBOX - tbase);
  const int nch = (nbox_tile + CHUNK - 1) / CHUNK;

  for (int i = tid; i < NBINS; i += 256) hist[i] = 0u;

  float4 regs[3];
  // prologue: load chunk 0 into buf[0]
  {
    int nb0c = min(CHUNK, nbox_tile);
    const float* cp = chunk_ptr(img, tbase, p0, p1, p2);
    int nv = (nb0c * NCH) / 4;   // <= 680
    const float4* cp4 = (const float4*)cp;
    float4* b4 = (float4*)&buf[0][0];
    #pragma unroll
    for (int k = 0; k < 3; ++k) { int i = tid + k * 256; if (i < nv) regs[k] = cp4[i]; }
    #pragma unroll
    for (int k = 0; k < 3; ++k) { int i = tid + k * 256; if (i < nv) b4[i] = regs[k]; }
  }
  __syncthreads();

  for (int c = 0; c < nch; ++c) {
    int nvN = 0;
    if (c + 1 < nch) {
      int fb = tbase + (c + 1) * CHUNK;
      int nbN = min(CHUNK, NBOX - fb);
      const float* cp = chunk_ptr(img, fb, p0, p1, p2);
      nvN = (nbN * NCH) / 4;
      const float4* cp4 = (const float4*)cp;
      #pragma unroll
      for (int k = 0; k < 3; ++k) { int i = tid + k * 256; if (i < nvN) regs[k] = cp4[i]; }
    }
    {
      int nb = min(CHUNK, nbox_tile - c * CHUNK);
      int b = tid >> 3, part = tid & 7;
      if (b < nb) {
        const float* row = &buf[c & 1][b * NCH];
        float obj = ref_sigmoid(row[4]);
        int mb = 0;
        if (obj > 0.25f) {
          float rr = 0.25f / obj;
          float tcons = __logf(rr / (1.0f - rr)) - 0.01f;   // conservative pre-filter
          #pragma unroll
          for (int cc = 0; cc < 10; ++cc) {
            float x = row[5 + part + 8 * cc];
            if (x > tcons) {
              float s = obj * ref_sigmoid(x);               // exact path
              if (s > 0.25f) {
                int bin = (int)((s - 0.25f) * BIN_SCALE);
                bin = min(bin, NBINS - 1);
                atomicAdd(&hist[bin], 1u);
                mb = max(mb, bin + 1);                      // stored = maxbin+1, 0 = none
              }
            }
          }
        }
        mb = max(mb, __shfl_xor(mb, 1, 8));
        mb = max(mb, __shfl_xor(mb, 2, 8));
        mb = max(mb, __shfl_xor(mb, 4, 8));
        if (part == 0)
          maxbin[(size_t)img * NBOX + tbase + c * CHUNK + b] = (unsigned short)mb;
      }
    }
    if (c + 1 < nch) {
      float4* b4 = (float4*)&buf[(c + 1) & 1][0];
      #pragma unroll
      for (int k = 0; k < 3; ++k) { int i = tid + k * 256; if (i < nvN) b4[i] = regs[k]; }
    }
    __syncthreads();
  }

  for (int i = tid; i < NBINS; i += 256) {
    unsigned int v = hist[i];
    if (v) atomicAdd(&ghist[img * NBINS + i], v);
  }
}

// ---------------- per-image threshold bin (parallel scan, 16 blocks) ----------------
__global__ __launch_bounds__(256) void k_thresh(const unsigned int* __restrict__ ghist,
                                                int* __restrict__ tbin) {
  __shared__ unsigned int h[NBINS];
  __shared__ unsigned int psum[256];
  const int tid = threadIdx.x;
  const int img = blockIdx.x;

  for (int i = tid; i < NBINS; i += 256) h[i] = ghist[img * NBINS + i];
  __syncthreads();
  unsigned int ps = 0;
  for (int k = 0; k < 16; ++k) ps += h[tid * 16 + k];
  psum[tid] = ps;
  __syncthreads();
  if (tid == 0) {
    long long cum = 0;
    int tb = 0;
    bool found = false;
    for (int g = 255; g >= 0 && !found; --g) {
      if (cum + (long long)psum[g] >= NTOP) {
        for (int b = g * 16 + 15; b >= g * 16; --b) {
          cum += h[b];
          if (cum >= NTOP) { tb = b; found = true; break; }
        }
      } else {
        cum += psum[g];
      }
    }
    if (!found) tb = 0;
    while (cum > CAP && tb < NBINS - 1) { cum -= h[tb]; ++tb; }
    tbin[img] = tb;
  }
}

// ---------------- worklist: compact passing rows (dense, coalesced) ----------------
__global__ __launch_bounds__(256) void k_worklist(const unsigned short* __restrict__ maxbin,
    const int* __restrict__ tbin, unsigned int* __restrict__ worklist,
    int* __restrict__ wcnt) {
  __shared__ int lcnt;
  __shared__ int lbase;
  const int tid = threadIdx.x;
  if (tid == 0) lcnt = 0;
  __syncthreads();
  int idx = blockIdx.x * 256 + tid;
  bool pass = false;
  int my = 0;
  int img = 0, box = 0;
  if (idx < NIMG * NBOX) {
    img = idx / NBOX;
    box = idx - img * NBOX;
    int mb = (int)maxbin[idx];
    if (mb > tbin[img]) {            // mb = maxbin+1 > tb  <=>  maxbin >= tb
      pass = true;
      my = atomicAdd(&lcnt, 1);
    }
  }
  __syncthreads();
  if (tid == 0 && lcnt > 0) lbase = atomicAdd(wcnt, lcnt);
  __syncthreads();
  if (pass) {
    int pos = lbase + my;
    if (pos < WLCAP) worklist[pos] = ((unsigned int)img << 16) | (unsigned int)box;
  }
}

// ---------------- emit: one dense row per thread, exact keys ----------------
__global__ __launch_bounds__(256) void k_emit(const float* __restrict__ p0,
    const float* __restrict__ p1, const float* __restrict__ p2,
    const unsigned int* __restrict__ worklist, const int* __restrict__ wcnt,
    const int* __restrict__ tbin, unsigned long long* __restrict__ cand,
    int* __restrict__ cnt) {
  int n = *wcnt;
  if (n > WLCAP) n = WLCAP;
  const int nthreads = gridDim.x * 256;
  for (int i = blockIdx.x * 256 + threadIdx.x; i < n; i += nthreads) {
    unsigned int e = worklist[i];
    int img = (int)(e >> 16);
    int box = (int)(e & 0xFFFFu);
    int lvl, gx, gy, anc; float stride;
    const float* ptr = locate(img, box, p0, p1, p2, lvl, gx, gy, anc, stride);
    float obj = ref_sigmoid(ptr[4]);
    if (obj <= 0.25f) continue;
    int tb = tbin[img];
    float rr = 0.25f / obj;
    float tcons = __logf(rr / (1.0f - rr)) - 0.01f;
    #pragma unroll 8
    for (int c = 0; c < NCLS; ++c) {
      float x = ptr[5 + c];
      if (x <= tcons) continue;
      float s = obj * ref_sigmoid(x);
      if (s > 0.25f) {
        int bin = (int)((s - 0.25f) * BIN_SCALE);
        bin = min(bin, NBINS - 1);
        if (bin >= tb) {
          int pos = atomicAdd(&cnt[img], 1);
          if (pos < CAP) {
            unsigned int fi = (unsigned int)(box * NCLS + c);
            unsigned long long key =
                ((unsigned long long)__float_as_uint(s) << 32) |
                (unsigned long long)(0xFFFFFFFFu - fi);
            cand[(size_t)img * CAP + pos] = key;
          }
        }
      }
    }
  }
}

// ---------------- fused sort + NMS (one block per image) ----------------
// swizzled LDS index: pad every 16 u64 keys to break the i/i+16 bank aliasing
#define SIDX(i) ((i) + ((i) >> 4))

__global__ __launch_bounds__(1024) void k_sortnms(const float* __restrict__ p0,
    const float* __restrict__ p1, const float* __restrict__ p2,
    const float* __restrict__ anchors, const unsigned long long* __restrict__ cand,
    const int* __restrict__ cnt_arr, const float* __restrict__ scalef,
    float* __restrict__ out) {
  __shared__ unsigned long long keys[CAP + CAP / 16];   // 34.8 KB (swizzled)
  __shared__ float bxs[NTOP][4];             // 16 KB
  __shared__ float val[NTOP];                //  4 KB
  __shared__ int   lab[NTOP];                //  4 KB
  __shared__ int   n2_sh, cnt_sh;
  const int tid = threadIdx.x;
  const int img = blockIdx.x;

  if (tid == 0) {
    int c = cnt_arr[img];
    c = max(0, min(c, CAP));
    int n2 = 1024;
    while (n2 < c) n2 <<= 1;
    cnt_sh = c; n2_sh = n2;
  }
  __syncthreads();
  const int cnt = cnt_sh;
  const int n2  = n2_sh;

  const unsigned long long* c = cand + (size_t)img * CAP;
  for (int i = tid; i < n2; i += 1024) keys[SIDX(i)] = (i < cnt) ? c[i] : 0ull;
  __syncthreads();

  for (int kk = 2; kk <= n2; kk <<= 1) {
    for (int j = kk >> 1; j > 0; j >>= 1) {
      for (int i = tid; i < n2; i += 1024) {
        int l = i ^ j;
        if (l > i) {
          unsigned long long a = keys[SIDX(i)], b = keys[SIDX(l)];
          bool up = ((i & kk) == 0);
          bool sw = up ? (a < b) : (a > b);
          if (sw) { keys[SIDX(i)] = b; keys[SIDX(l)] = a; }
        }
      }
      __syncthreads();
    }
  }

  // decode top-1000
  if (tid < NTOP) {
    unsigned long long key = keys[SIDX(tid)];
    unsigned int v = (unsigned int)(key >> 32);
    val[tid] = __uint_as_float(v);
    if (v) {
      unsigned int idx = 0xFFFFFFFFu - (unsigned int)(key & 0xFFFFFFFFu);
      int box = (int)(idx / NCLS);
      int l   = (int)(idx % NCLS);
      lab[tid] = l;
      int lvl, gx, gy, anc; float stride;
      const float* ptr = locate(img, box, p0, p1, p2, lvl, gx, gy, anc, stride);
      float sx = ref_sigmoid(ptr[0]);
      float sy = ref_sigmoid(ptr[1]);
      float sw = ref_sigmoid(ptr[2]);
      float sh = ref_sigmoid(ptr[3]);
      float aw = anchors[(lvl * 3 + anc) * 2 + 0];
      float ah = anchors[(lvl * 3 + anc) * 2 + 1];
      float cx = (2.0f * sx - 0.5f + (float)gx) * stride;
      float cy = (2.0f * sy - 0.5f + (float)gy) * stride;
      float ww = (4.0f * (sw * sw)) * aw;
      float hh = (4.0f * (sh * sh)) * ah;
      bxs[tid][0] = clip640(cx - ww * 0.5f);
      bxs[tid][1] = clip640(cy - hh * 0.5f);
      bxs[tid][2] = clip640(cx + ww * 0.5f);
      bxs[tid][3] = clip640(cy + hh * 0.5f);
    } else {
      lab[tid] = -1;
      bxs[tid][0] = bxs[tid][1] = bxs[tid][2] = bxs[tid][3] = 0.0f;
    }
  }
  __syncthreads();
  if (tid >= 64) return;

  // wave-0 NMS: lane l owns entries [l*16, l*16+16), box data in REGISTERS
  const int l = tid;
  const float scf = scalef[img];
  float rb0[16], rb1[16], rb2[16], rb3[16];
  int rlab[16];
  unsigned int amask = 0u;
  #pragma unroll
  for (int k = 0; k < 16; ++k) {
    int t = l * 16 + k;
    if (t < NTOP) {
      rb0[k] = bxs[t][0]; rb1[k] = bxs[t][1];
      rb2[k] = bxs[t][2]; rb3[k] = bxs[t][3];
      rlab[k] = lab[t];
      if (val[t] > 0.0f) amask |= (1u << k);
    } else {
      rb0[k] = rb1[k] = rb2[k] = rb3[k] = 0.0f;
      rlab[k] = -1;
    }
  }

  for (int i = 0; i < NDET; ++i) {
    unsigned long long bal = __ballot(amask != 0u);
    float* orow = out + ((size_t)img * NDET + i) * 6;
    if (bal == 0ull) {
      if (l == 0) {
        orow[0] = 0.0f; orow[1] = 0.0f; orow[2] = 0.0f;
        orow[3] = 0.0f; orow[4] = 0.0f; orow[5] = -1.0f;
      }
      continue;
    }
    int L = __ffsll((unsigned long long)bal) - 1;
    unsigned int mL = (unsigned int)__shfl((int)amask, L);
    int j = L * 16 + (__ffs(mL) - 1);

    // broadcast reads (same address on all lanes -> no conflicts)
    float b0 = bxs[j][0], b1 = bxs[j][1], b2 = bxs[j][2], b3 = bxs[j][3];
    int lj = lab[j];
    if (l == 0) {
      orow[0] = b0 / scf; orow[1] = b1 / scf;
      orow[2] = b2 / scf; orow[3] = b3 / scf;
      orow[4] = val[j];
      orow[5] = (float)lj;
    }
    float off = (float)lj * 4096.0f;
    float a0 = b0 + off, a1 = b1 + off, a2 = b2 + off, a3 = b3 + off;
    float areaA = (a2 - a0) * (a3 - a1);
    #pragma unroll
    for (int k = 0; k < 16; ++k) {
      if (!((amask >> k) & 1u)) continue;
      if (rlab[k] != lj) continue;              // cross-class IoU exactly 0 in ref
      float o0 = rb0[k] + off, o1 = rb1[k] + off;
      float o2 = rb2[k] + off, o3 = rb3[k] + off;
      float ltx = fmaxf(a0, o0);
      float lty = fmaxf(a1, o1);
      float rbx = fminf(a2, o2);
      float rby = fminf(a3, o3);
      float wx = fmaxf(rbx - ltx, 0.0f);
      float wy = fmaxf(rby - lty, 0.0f);
      float inter = wx * wy;
      float a2r = (o2 - o0) * (o3 - o1);
      float denom = areaA + a2r - inter + 1e-7f;
      float iou = inter / denom;
      if (iou > 0.45f) amask &= ~(1u << k);     // includes t==j (ref self-suppression quirk)
    }
  }
}

// ---------------- launcher ----------------
extern "C" void kernel_launch(void* const* d_in, const int* in_sizes, int n_in,
                              void* d_out, int out_size, void* d_ws, size_t ws_size,
                              hipStream_t stream) {
  const float* p0 = (const float*)d_in[0];
  const float* p1 = (const float*)d_in[1];
  const float* p2 = (const float*)d_in[2];
  const float* anchors = (const float*)d_in[3];
  const float* scalef  = (const float*)d_in[4];
  float* out = (float*)d_out;

  char* w = (char*)d_ws;
  // layout (bytes): ghist 262144 | cnt 64 | tbin 64 | wcnt 64 | cand 524288 |
  //                 maxbin 806400 | worklist 262144   (~1.86 MB)
  unsigned int* ghist = (unsigned int*)(w);
  int* cnt  = (int*)(w + 262144);
  int* tbin = (int*)(w + 262208);
  int* wcnt = (int*)(w + 262272);
  unsigned long long* cand = (unsigned long long*)(w + 262336);
  unsigned short* maxbin = (unsigned short*)(w + 262336 + 524288);       // 786624
  unsigned int* worklist = (unsigned int*)(w + 786624 + 806400);         // 1593024

  hipMemsetAsync(ghist, 0, 262144 + 192, stream);   // hist + cnt + tbin + wcnt

  k_passA<<<dim3(NIMG * TILES), dim3(256), 0, stream>>>(p0, p1, p2, ghist, maxbin);
  k_thresh<<<dim3(NIMG), dim3(256), 0, stream>>>(ghist, tbin);
  k_worklist<<<dim3((NIMG * NBOX + 255) / 256), dim3(256), 0, stream>>>(maxbin, tbin, worklist, wcnt);
  k_emit<<<dim3(256), dim3(256), 0, stream>>>(p0, p1, p2, worklist, wcnt, tbin, cand, cnt);
  k_sortnms<<<dim3(NIMG), dim3(1024), 0, stream>>>(p0, p1, p2, anchors, cand, cnt, scalef, out);
}